// Round 8
// baseline (196.207 us; speedup 1.0000x reference)
//
#include <hip/hip_runtime.h>

#define B    64
#define K    512
#define C    4
#define NL   5
#define BK   (B*K)
#define ROWS 64             // rows of Habs2 per block (octet split)
#define NT   512            // threads per block (8 waves)
#define GRID (B*8)          // 512 blocks = 2 per CU (two sync domains/CU)

typedef _Float16 half_t;
typedef _Float16 half8 __attribute__((ext_vector_type(8)));

// ---- LDS layout (bytes). PAD sizes the block to ~60 KB so exactly 2 blocks
// fit per CU (3x would exceed 160 KiB) -> deterministic 2 sync domains/CU.
#define PART_OFF   0                     // float[8][512] per-wave P2 slices
#define VST_OFF    (8*K*4)               // float2[512]
#define XSQ_OFF    (VST_OFF + K*8)       // float[512]
#define MPL_OFF    (XSQ_OFF + K*4)       // float[512]
#define NZ_OFF     (MPL_OFF + K*4)       // float[64]
#define DAB_OFF    (NZ_OFF + ROWS*4)     // float[64]
#define PAD_OFF    (DAB_OFF + ROWS*4)
#define SMEM_BYTES (PAD_OFF + 36864)     // 61952 B; 2x=124KB<=160KB, 3x>160KB

// ---- L3-direct (bypass L1/L2) data ops: relaxed agent-scope atomics --------
__device__ __forceinline__ float ld_l3(const float* p) {
    return __uint_as_float(__hip_atomic_load((const unsigned*)p,
        __ATOMIC_RELAXED, __HIP_MEMORY_SCOPE_AGENT));
}
__device__ __forceinline__ void st_l3(float* p, float v) {
    __hip_atomic_store((unsigned*)p, __float_as_uint(v),
        __ATOMIC_RELAXED, __HIP_MEMORY_SCOPE_AGENT);
}
__device__ __forceinline__ void st_l3_2(float2* p, float2 v) {
    unsigned long long u = ((unsigned long long)__float_as_uint(v.y) << 32)
                         | (unsigned long long)__float_as_uint(v.x);
    __hip_atomic_store((unsigned long long*)p, u,
        __ATOMIC_RELAXED, __HIP_MEMORY_SCOPE_AGENT);
}
__device__ __forceinline__ float2 ld_l3_2(const float2* p) {
    unsigned long long u = __hip_atomic_load((const unsigned long long*)p,
        __ATOMIC_RELAXED, __HIP_MEMORY_SCOPE_AGENT);
    return make_float2(__uint_as_float((unsigned)(u & 0xffffffffu)),
                       __uint_as_float((unsigned)(u >> 32)));
}

// ---- DPP wave64 sum reduction (VALU pipe, zero LDS traffic) ---------------
template <int CTRL, int ROWMASK>
__device__ __forceinline__ float dppadd(float x) {
    int t = __builtin_amdgcn_update_dpp(0, __float_as_int(x), CTRL, ROWMASK,
                                        0xf, true);
    return x + __int_as_float(t);
}
__device__ __forceinline__ float wsum(float x) {
    x = dppadd<0x111, 0xf>(x);   // row_shr:1
    x = dppadd<0x112, 0xf>(x);   // row_shr:2
    x = dppadd<0x114, 0xf>(x);   // row_shr:4
    x = dppadd<0x118, 0xf>(x);   // row_shr:8
    x = dppadd<0x142, 0xa>(x);   // row_bcast:15 -> rows 1,3
    x = dppadd<0x143, 0xc>(x);   // row_bcast:31 -> rows 2,3
    return __int_as_float(__builtin_amdgcn_readlane(__float_as_int(x), 63));
}

// ---------------------------------------------------------------------------
// Octet-split persistent kernel, 2 independent sync domains per CU.
// Block (batch = blockIdx>>3, oct = blockIdx&7) owns rows j0..j0+63 of its
// batch, register-resident as fp16 (wave w holds rows {8i+w}, cols t*64+lane).
// The two co-resident blocks on a CU belong to different batches -> when one
// stalls in its octet exchange barrier, the other computes (CU-level latency
// hiding). All LDS accesses lane-consecutive (conflict-free); reductions via
// DPP; cross-block exchange via L3-direct sc1 ops + fence-free monotonic
// octet barrier. FIN redundant x8 keeps vst/xsq block-local; all 8 waves
// participate in every phase (tid<K everywhere).
// ---------------------------------------------------------------------------
__global__ __launch_bounds__(NT, 4) void k_all(
    const float* __restrict__ hre,  const float* __restrict__ him,
    const float* __restrict__ noise,const float* __restrict__ mp,
    const float* __restrict__ vre,  const float* __restrict__ vim,
    const float* __restrict__ ar_re,const float* __restrict__ ar_im,
    const float* __restrict__ dl_re,const float* __restrict__ dl_im,
    const float* __restrict__ rc_re,const float* __restrict__ rc_im,
    float2* __restrict__ vtilde,    // [2][BK]
    float*  __restrict__ ulpart,    // [2][B*8][K]
    unsigned* __restrict__ bar,     // 64 octets x 32 uints (128 B)
    float* __restrict__ out)        // [NL][BK][2]
{
    extern __shared__ char smem[];
    float*  part = (float*) (smem + PART_OFF);
    float2* vst  = (float2*)(smem + VST_OFF);
    float*  xsq  = (float*) (smem + XSQ_OFF);
    float*  mpl  = (float*) (smem + MPL_OFF);
    float*  nz   = (float*) (smem + NZ_OFF);
    float*  dab  = (float*) (smem + DAB_OFF);

    const int tid  = threadIdx.x;
    const int lane = tid & 63;
    const int w    = tid >> 6;                 // wave 0..7
    const int bt   = blockIdx.x >> 3;          // batch 0..63
    const int oct  = blockIdx.x & 7;           // octant 0..7
    const int j0   = oct * ROWS;
    unsigned* qb   = bar + ((unsigned)bt << 5);

    // ---------------- init: v state, |v|^2, maxpow, noise -------------------
    {
        float a = vre[bt * K + tid], c2 = vim[bt * K + tid];
        vst[tid] = make_float2(a, c2);
        xsq[tid] = a * a + c2 * c2;
        mpl[tid] = mp[bt * K + tid];
        if (tid < ROWS) nz[tid] = noise[bt * K + j0 + tid];
    }
    __syncthreads();

    float xq[8];
#pragma unroll
    for (int t = 0; t < 8; ++t) xq[t] = xsq[t * 64 + lane];

    // ---------------- HBM stream -> register fragments + fused layer-0 P1 --
    half8 h[8];                                   // rows {8i+w}, cols t*64+lane
    float rs0[8];                                 // uniform row sums (l=0)
    {
        const size_t gb = ((size_t)bt * K + j0) * K;
        float ra[2][8], ia[2][8];
#pragma unroll
        for (int t = 0; t < 8; ++t) {
            ra[0][t] = __builtin_nontemporal_load(hre + gb + (size_t)w * K + t * 64 + lane);
            ia[0][t] = __builtin_nontemporal_load(him + gb + (size_t)w * K + t * 64 + lane);
        }
#pragma unroll
        for (int i = 0; i < 8; ++i) {
            const int cur = i & 1, nxt = cur ^ 1;
            if (i < 7) {
                const size_t rb = gb + (size_t)(8 * (i + 1) + w) * K;
#pragma unroll
                for (int t = 0; t < 8; ++t) {
                    ra[nxt][t] = __builtin_nontemporal_load(hre + rb + t * 64 + lane);
                    ia[nxt][t] = __builtin_nontemporal_load(him + rb + t * 64 + lane);
                }
            }
            float s[8], acc = 0.f;
            half8 hh;
#pragma unroll
            for (int t = 0; t < 8; ++t) {
                s[t]  = ra[cur][t] * ra[cur][t] + ia[cur][t] * ia[cur][t];
                hh[t] = (_Float16)s[t];
                acc  += s[t] * xq[t];
            }
            h[i] = hh;
            const int row = 8 * i + w;            // local row 0..63
            const int j   = j0 + row;             // diag at global col j
            if (lane == (j & 63)) dab[row] = s[j >> 6];
            rs0[i] = wsum(acc);                   // fused layer-0 P1
        }
    }

    for (int l = 0; l < NL; ++l) {
        const int buf = l & 1;
        // ---------------- P1: row sums (regs + DPP -> SGPR) ----------------
        float scov[8];
        if (l == 0) {
#pragma unroll
            for (int r = 0; r < 8; ++r) scov[r] = rs0[r];
        } else {
#pragma unroll
            for (int t = 0; t < 8; ++t) xq[t] = xsq[t * 64 + lane];
#pragma unroll
            for (int r = 0; r < 8; ++r) {
                float acc = 0.f;
#pragma unroll
                for (int t = 0; t < 8; ++t) acc += (float)h[r][t] * xq[t];
                scov[r] = wsum(acc);
            }
        }
        // ---------------- per-row algebra: lane r owns row 8*r + w ---------
        float ulv_own = 0.f;
        if (lane < 8) {
            float s = scov[0];
#pragma unroll
            for (int r = 1; r < 8; ++r) s = (lane == r) ? scov[r] : s;
            const int row = 8 * lane + w;
            const int j   = j0 + row;
            const int bj  = bt * K + j;
            const float cov = s + nz[row];
            const float d2  = dab[row];
            const float A   = d2 * xsq[j];
            const float ww  = cov / (cov - A);    // w is real, > 0
            const float sc  = d2 * ww / cov;
            const float2 vv = vst[j];
            st_l3_2(&vtilde[buf * BK + bj], make_float2(sc * vv.x, sc * vv.y));
            ulv_own = A * ww / (cov * cov);       // |u|^2 |w|
        }
        float ulv[8];                             // uniform (SGPR)
#pragma unroll
        for (int r = 0; r < 8; ++r)
            ulv[r] = __int_as_float(
                __builtin_amdgcn_readlane(__float_as_int(ulv_own), r));

        // ---------------- P2: transposed matvec from register fragments ----
#pragma unroll
        for (int t = 0; t < 8; ++t) {
            float a = 0.f;
#pragma unroll
            for (int r = 0; r < 8; ++r) a += (float)h[r][t] * ulv[r];
            part[w * K + t * 64 + lane] = a;      // lane-consecutive
        }
        __syncthreads();                          // sync 1

        float s2 = 0.f;                           // own octet partial (k=tid)
#pragma unroll
        for (int ws2 = 0; ws2 < 8; ++ws2) s2 += part[ws2 * K + tid];
        st_l3(&ulpart[(size_t)buf * (B*8*K) + ((size_t)(bt*8 + oct)) * K + tid],
              s2);
        __syncthreads();                          // sync 2: drain st_l3
        if (tid == 0)
            __hip_atomic_fetch_add(qb, 1u, __ATOMIC_RELAXED,
                                   __HIP_MEMORY_SCOPE_AGENT);
        if (lane == 0) {                          // per-wave poll exit
            const unsigned target = 8u * (unsigned)(l + 1);
            while (__hip_atomic_load(qb, __ATOMIC_RELAXED,
                                     __HIP_MEMORY_SCOPE_AGENT) < target)
                __builtin_amdgcn_s_sleep(2);
        }
        asm volatile("" ::: "memory");            // no hoisting past poll

        // ---------------- FIN: whole batch row (redundant x8), k = tid -----
        {
            const int k  = tid;
            const int bk = bt * K + k;
            const float* up = ulpart + (size_t)buf * (B*8*K) + (size_t)(bt*8) * K;
            const float2 vt = ld_l3_2(&vtilde[buf * BK + bk]);
            float ul = s2;                        // own partial: register
#pragma unroll
            for (int oo = 0; oo < 8; ++oo)
                if (oo != oct) ul += ld_l3(up + oo * K + k);
            const float p   = mpl[k];
            const float avt = sqrtf(vt.x*vt.x + vt.y*vt.y);
            const float mu  = fmaxf(avt / sqrtf(p) - ul, 0.f);
            const float inv = 1.f / (ul + mu);
            float ax = 0.f, ay = 0.f;
#pragma unroll
            for (int c = 0; c < C; ++c) {
                const float gre = ar_re[c] * inv + dl_re[c];
                const float gim = ar_im[c] * inv + dl_im[c];
                float zre = vt.x * gre - vt.y * gim;
                float zim = vt.x * gim + vt.y * gre;
                zre = fmaxf(zre, 0.f);            // CReLU
                zim = fmaxf(zim, 0.f);
                ax += zre * rc_re[c] - zim * rc_im[c];
                ay += zre * rc_im[c] + zim * rc_re[c];
            }
            const float n2   = ax*ax + ay*ay;
            const float cur  = fmaxf(p, n2);
            const float corr = fminf(sqrtf(p / cur), 1.f);
            ax *= corr; ay *= corr;
            if ((k >> 6) == oct)                  // owner octant writes out
                ((float2*)out)[(size_t)l * BK + bk] = make_float2(ax, ay);
            vst[k] = make_float2(ax, ay);
            xsq[k] = ax * ax + ay * ay;
        }
        __syncthreads();                          // sync 3
    }
}

// ---------------------------------------------------------------------------
extern "C" void kernel_launch(void* const* d_in, const int* in_sizes, int n_in,
                              void* d_out, int out_size, void* d_ws, size_t ws_size,
                              hipStream_t stream) {
    const float* hre   = (const float*)d_in[0];
    const float* him   = (const float*)d_in[1];
    const float* noise = (const float*)d_in[2];
    const float* mp    = (const float*)d_in[3];
    const float* vre   = (const float*)d_in[4];
    const float* vim   = (const float*)d_in[5];
    const float* ar_re = (const float*)d_in[6];
    const float* ar_im = (const float*)d_in[7];
    const float* dl_re = (const float*)d_in[8];
    const float* dl_im = (const float*)d_in[9];
    const float* rc_re = (const float*)d_in[10];
    const float* rc_im = (const float*)d_in[11];
    float* out = (float*)d_out;

    char*     ws     = (char*)d_ws;
    float2*   vtilde = (float2*)ws;                               // 512 KB
    float*    ulpart = (float*)(ws + 2*(size_t)BK*8);             // 2 MB
    unsigned* bar    = (unsigned*)(ws + 2*(size_t)BK*8 + 2*(size_t)B*8*K*4);

    static bool attr_done = false;
    if (!attr_done) {
        (void)hipFuncSetAttribute((const void*)k_all,
                                  hipFuncAttributeMaxDynamicSharedMemorySize,
                                  SMEM_BYTES);
        attr_done = true;
    }

    // monotonic barrier counters must be zero at kernel start on every replay
    (void)hipMemsetAsync(bar, 0, B * 32 * sizeof(unsigned), stream);

    hipLaunchKernelGGL(k_all, dim3(GRID), dim3(NT), SMEM_BYTES, stream,
                       hre, him, noise, mp, vre, vim,
                       ar_re, ar_im, dl_re, dl_im, rc_re, rc_im,
                       vtilde, ulpart, bar, out);
}

// Round 9
// 193.184 us; speedup vs baseline: 1.0156x; 1.0156x over previous
//
#include <hip/hip_runtime.h>

#define B    64
#define K    512
#define C    4
#define NL   5
#define BK   (B*K)
#define ROWS 128            // rows of Habs2 per block (quartet split)
#define NT   1024           // threads per block (16 waves)
#define GRID (B*4)          // 256 blocks = 1 per CU

typedef _Float16 half_t;
typedef _Float16 half8 __attribute__((ext_vector_type(8)));

// ---- LDS layout (bytes). part oversized so block footprint >80 KiB ->
// exactly 1 block/CU (deterministic, even spread across 256 CUs).
#define PART_OFF   0                     // float[16(+20 pad)][512]
#define VST_OFF    (36*K*4)              // float2[512]
#define XSQ_OFF    (VST_OFF + K*8)       // float[512]
#define MPL_OFF    (XSQ_OFF + K*4)       // float[512]
#define NZ_OFF     (MPL_OFF + K*4)       // float[128]
#define DAB_OFF    (NZ_OFF + ROWS*4)     // float[128]
#define SMEM_BYTES (DAB_OFF + ROWS*4)    // 82944 B

// ---- L3-direct (bypass L1/L2) data ops: relaxed agent-scope atomics --------
__device__ __forceinline__ float ld_l3(const float* p) {
    return __uint_as_float(__hip_atomic_load((const unsigned*)p,
        __ATOMIC_RELAXED, __HIP_MEMORY_SCOPE_AGENT));
}
__device__ __forceinline__ void st_l3_2(float2* p, float2 v) {
    unsigned long long u = ((unsigned long long)__float_as_uint(v.y) << 32)
                         | (unsigned long long)__float_as_uint(v.x);
    __hip_atomic_store((unsigned long long*)p, u,
        __ATOMIC_RELAXED, __HIP_MEMORY_SCOPE_AGENT);
}
__device__ __forceinline__ float2 ld_l3_2(const float2* p) {
    unsigned long long u = __hip_atomic_load((const unsigned long long*)p,
        __ATOMIC_RELAXED, __HIP_MEMORY_SCOPE_AGENT);
    return make_float2(__uint_as_float((unsigned)(u & 0xffffffffu)),
                       __uint_as_float((unsigned)(u >> 32)));
}

// ---- DPP wave64 sum reduction (VALU pipe, zero LDS traffic) ---------------
template <int CTRL, int ROWMASK>
__device__ __forceinline__ float dppadd(float x) {
    int t = __builtin_amdgcn_update_dpp(0, __float_as_int(x), CTRL, ROWMASK,
                                        0xf, true);
    return x + __int_as_float(t);
}
__device__ __forceinline__ float wsum(float x) {
    x = dppadd<0x111, 0xf>(x);   // row_shr:1
    x = dppadd<0x112, 0xf>(x);   // row_shr:2
    x = dppadd<0x114, 0xf>(x);   // row_shr:4
    x = dppadd<0x118, 0xf>(x);   // row_shr:8
    x = dppadd<0x142, 0xa>(x);   // row_bcast:15 -> rows 1,3
    x = dppadd<0x143, 0xc>(x);   // row_bcast:31 -> rows 2,3
    return __int_as_float(__builtin_amdgcn_readlane(__float_as_int(x), 63));
}

// ---------------------------------------------------------------------------
// Quartet-split persistent kernel, BARRIER-FREE tagged-dataflow exchange.
// Block (b = blockIdx&63, q = blockIdx>>6) owns rows j0..j0+127 of batch b,
// register-resident fp16 (wave w: rows {16i+w}, cols t*64+lane -> every LDS
// access lane-consecutive, conflict-free). Per layer: P1 dot (regs+DPP) ->
// per-row algebra; P2 transposed matvec (regs) -> LDS reduce -> store the
// quartet partial as an 8-byte atomic {value, tag=l+1}. FIN polls the tagged
// partials DIRECTLY (poll == read: one L3 hop replaces the old
// arrival+detect+read chain; each octant consumed as soon as it lands).
// Safety: 8B atomicity; monotonic tags; sync1's implicit vmcnt(0) drain
// orders vtilde stores before the partial store (tag ==> vtilde visible);
// parity double-buffer is race-free because a writer at l+2 must have
// validated all l+1 partials, which implies every reader consumed l.
// Tags zeroed per replay by a 4 MB memset node.
// ---------------------------------------------------------------------------
__global__ __launch_bounds__(NT, 4) void k_all(
    const float* __restrict__ hre,  const float* __restrict__ him,
    const float* __restrict__ noise,const float* __restrict__ mp,
    const float* __restrict__ vre,  const float* __restrict__ vim,
    const float* __restrict__ ar_re,const float* __restrict__ ar_im,
    const float* __restrict__ dl_re,const float* __restrict__ dl_im,
    const float* __restrict__ rc_re,const float* __restrict__ rc_im,
    float2* __restrict__ vtilde,    // [2][BK]           (untagged)
    float2* __restrict__ ulpart,    // [2][B*4][K]       {value, tag}
    float* __restrict__ out)        // [NL][BK][2]
{
    extern __shared__ char smem[];
    float*  part = (float*) (smem + PART_OFF);
    float2* vst  = (float2*)(smem + VST_OFF);
    float*  xsq  = (float*) (smem + XSQ_OFF);
    float*  mpl  = (float*) (smem + MPL_OFF);
    float*  nz   = (float*) (smem + NZ_OFF);
    float*  dab  = (float*) (smem + DAB_OFF);

    const int tid  = threadIdx.x;
    const int lane = tid & 63;
    const int w    = tid >> 6;
    const int b    = blockIdx.x & 63;
    const int q    = blockIdx.x >> 6;
    const int j0   = q * ROWS;

    // ---------------- init: v state, |v|^2, maxpow, noise -------------------
    if (tid < K) {
        float a = vre[b * K + tid], c2 = vim[b * K + tid];
        vst[tid] = make_float2(a, c2);
        xsq[tid] = a * a + c2 * c2;
        mpl[tid] = mp[b * K + tid];
    } else if (tid < K + ROWS) {
        nz[tid - K] = noise[b * K + j0 + (tid - K)];
    }
    __syncthreads();

    float xq[8];
#pragma unroll
    for (int t = 0; t < 8; ++t) xq[t] = xsq[t * 64 + lane];

    // ---------------- HBM stream -> register fragments + fused layer-0 P1 --
    // Plain (cacheable) loads: inputs are re-read every graph replay and fit
    // L3 (134 MB vs 256 MB) -> let L3 keep them across replays.
    half8 h[8];
    float rs0[8];                                     // uniform row sums (l=0)
    {
        const size_t gb = ((size_t)b * K + j0) * K;
        float ra[2][8], ia[2][8];
#pragma unroll
        for (int t = 0; t < 8; ++t) {
            ra[0][t] = hre[gb + (size_t)w * K + t * 64 + lane];
            ia[0][t] = him[gb + (size_t)w * K + t * 64 + lane];
        }
#pragma unroll
        for (int i = 0; i < 8; ++i) {
            const int cur = i & 1, nxt = cur ^ 1;
            if (i < 7) {
                const size_t rb = gb + (size_t)(16 * (i + 1) + w) * K;
#pragma unroll
                for (int t = 0; t < 8; ++t) {
                    ra[nxt][t] = hre[rb + t * 64 + lane];
                    ia[nxt][t] = him[rb + t * 64 + lane];
                }
            }
            float s[8], acc = 0.f;
            half8 hh;
#pragma unroll
            for (int t = 0; t < 8; ++t) {
                s[t]  = ra[cur][t] * ra[cur][t] + ia[cur][t] * ia[cur][t];
                hh[t] = (_Float16)s[t];
                acc  += s[t] * xq[t];
            }
            h[i] = hh;
            const int row = 16 * i + w;
            const int j   = j0 + row;                 // diag at global col j
            if (lane == (j & 63)) dab[row] = s[j >> 6];
            rs0[i] = wsum(acc);                       // fused layer-0 P1
        }
    }

    for (int l = 0; l < NL; ++l) {
        const int buf = l & 1;
        const unsigned tag = (unsigned)(l + 1);
        // ---------------- P1: row sums (regs + DPP -> SGPR) ----------------
        float scov[8];
        if (l == 0) {
#pragma unroll
            for (int r = 0; r < 8; ++r) scov[r] = rs0[r];
        } else {
#pragma unroll
            for (int t = 0; t < 8; ++t) xq[t] = xsq[t * 64 + lane];
#pragma unroll
            for (int r = 0; r < 8; ++r) {
                float acc = 0.f;
#pragma unroll
                for (int t = 0; t < 8; ++t) acc += (float)h[r][t] * xq[t];
                scov[r] = wsum(acc);
            }
        }
        // ---------------- per-row algebra: lane r owns row 16*r + w --------
        float ulv_own = 0.f;
        if (lane < 8) {
            float s = scov[0];
#pragma unroll
            for (int r = 1; r < 8; ++r) s = (lane == r) ? scov[r] : s;
            const int row = 16 * lane + w;
            const int j   = j0 + row;
            const int bj  = b * K + j;
            const float cov = s + nz[row];
            const float d2  = dab[row];
            const float A   = d2 * xsq[j];
            const float ww  = cov / (cov - A);        // w is real, > 0
            const float sc  = d2 * ww / cov;
            const float2 vv = vst[j];
            st_l3_2(&vtilde[buf * BK + bj], make_float2(sc * vv.x, sc * vv.y));
            ulv_own = A * ww / (cov * cov);           // |u|^2 |w|
        }
        float ulv[8];                                 // uniform (SGPR)
#pragma unroll
        for (int r = 0; r < 8; ++r)
            ulv[r] = __int_as_float(
                __builtin_amdgcn_readlane(__float_as_int(ulv_own), r));

        // ---------------- P2: transposed matvec from register fragments ----
#pragma unroll
        for (int t = 0; t < 8; ++t) {
            float a = 0.f;
#pragma unroll
            for (int r = 0; r < 8; ++r) a += (float)h[r][t] * ulv[r];
            part[w * K + t * 64 + lane] = a;          // lane-consecutive
        }
        __syncthreads();      // sync1 (also drains vtilde stores: vmcnt(0))

        float s2 = 0.f;                               // own quartet partial
        if (tid < K) {
#pragma unroll
            for (int ws2 = 0; ws2 < 16; ++ws2) s2 += part[ws2 * K + tid];
            st_l3_2(&ulpart[(size_t)buf * (B*4*K) + ((size_t)(b*4 + q)) * K + tid],
                    make_float2(s2, __uint_as_float(tag)));
        }
        asm volatile("" ::: "memory");

        // ---------------- FIN: poll tagged partials, whole batch row -------
        if (tid < K) {
            const int k  = tid;
            const int bk = b * K + k;
            const float2* up = ulpart + (size_t)buf * (B*4*K) + (size_t)(b*4) * K;
            const int q1 = (q + 1) & 3, q2 = (q + 2) & 3, q3 = (q + 3) & 3;
            float2 va = ld_l3_2(up + q1 * K + k);     // 3 loads in flight
            float2 vb = ld_l3_2(up + q2 * K + k);
            float2 vc = ld_l3_2(up + q3 * K + k);
            while (__float_as_uint(va.y) != tag) {
                __builtin_amdgcn_s_sleep(1);
                va = ld_l3_2(up + q1 * K + k);
            }
            while (__float_as_uint(vb.y) != tag) {
                __builtin_amdgcn_s_sleep(1);
                vb = ld_l3_2(up + q2 * K + k);
            }
            while (__float_as_uint(vc.y) != tag) {
                __builtin_amdgcn_s_sleep(1);
                vc = ld_l3_2(up + q3 * K + k);
            }
            float ul = s2 + va.x + vb.x + vc.x;
            // tags validated ==> owner's vtilde (stored before its sync1) is
            // L3-visible; own block's vtilde drained at own sync1.
            const float2 vt = ld_l3_2(&vtilde[buf * BK + bk]);
            const float p   = mpl[k];
            const float avt = sqrtf(vt.x*vt.x + vt.y*vt.y);
            const float mu  = fmaxf(avt / sqrtf(p) - ul, 0.f);
            const float inv = 1.f / (ul + mu);
            float ax = 0.f, ay = 0.f;
#pragma unroll
            for (int c = 0; c < C; ++c) {
                const float gre = ar_re[c] * inv + dl_re[c];
                const float gim = ar_im[c] * inv + dl_im[c];
                float zre = vt.x * gre - vt.y * gim;
                float zim = vt.x * gim + vt.y * gre;
                zre = fmaxf(zre, 0.f);                 // CReLU
                zim = fmaxf(zim, 0.f);
                ax += zre * rc_re[c] - zim * rc_im[c];
                ay += zre * rc_im[c] + zim * rc_re[c];
            }
            const float n2   = ax*ax + ay*ay;
            const float cur  = fmaxf(p, n2);
            const float corr = fminf(sqrtf(p / cur), 1.f);
            ax *= corr; ay *= corr;
            if ((k >> 7) == q)                         // owner writes out
                ((float2*)out)[(size_t)l * BK + bk] = make_float2(ax, ay);
            vst[k] = make_float2(ax, ay);
            xsq[k] = ax * ax + ay * ay;
        }
        __syncthreads();                               // sync3
    }
}

// ---------------------------------------------------------------------------
extern "C" void kernel_launch(void* const* d_in, const int* in_sizes, int n_in,
                              void* d_out, int out_size, void* d_ws, size_t ws_size,
                              hipStream_t stream) {
    const float* hre   = (const float*)d_in[0];
    const float* him   = (const float*)d_in[1];
    const float* noise = (const float*)d_in[2];
    const float* mp    = (const float*)d_in[3];
    const float* vre   = (const float*)d_in[4];
    const float* vim   = (const float*)d_in[5];
    const float* ar_re = (const float*)d_in[6];
    const float* ar_im = (const float*)d_in[7];
    const float* dl_re = (const float*)d_in[8];
    const float* dl_im = (const float*)d_in[9];
    const float* rc_re = (const float*)d_in[10];
    const float* rc_im = (const float*)d_in[11];
    float* out = (float*)d_out;

    char*   ws     = (char*)d_ws;
    float2* vtilde = (float2*)ws;                                 // 512 KB
    float2* ulpart = (float2*)(ws + 2*(size_t)BK*8);              // 4 MB

    static bool attr_done = false;
    if (!attr_done) {
        (void)hipFuncSetAttribute((const void*)k_all,
                                  hipFuncAttributeMaxDynamicSharedMemorySize,
                                  SMEM_BYTES);
        attr_done = true;
    }

    // tags (l+1 in 1..5) must be zero at kernel start on EVERY graph replay,
    // else stale tags from the previous replay validate instantly.
    (void)hipMemsetAsync(ulpart, 0, 2*(size_t)(B*4)*K*sizeof(float2), stream);

    hipLaunchKernelGGL(k_all, dim3(GRID), dim3(NT), SMEM_BYTES, stream,
                       hre, him, noise, mp, vre, vim,
                       ar_re, ar_im, dl_re, dl_im, rc_re, rc_im,
                       vtilde, ulpart, out);
}

// Round 10
// 179.453 us; speedup vs baseline: 1.0934x; 1.0765x over previous
//
#include <hip/hip_runtime.h>

#define B    64
#define K    512
#define C    4
#define NL   5
#define BK   (B*K)
#define ROWS 128            // rows of Habs2 per block (quartet split)
#define NT   1024           // threads per block (16 waves)
#define GRID (B*4)          // 256 blocks = 1 per CU

typedef _Float16 half_t;
typedef _Float16 half8 __attribute__((ext_vector_type(8)));
typedef float    f2    __attribute__((ext_vector_type(2)));

// ---- LDS layout (bytes). part oversized so block footprint >80 KiB ->
// exactly 1 block/CU (deterministic, even spread across 256 CUs).
#define PART_OFF   0                     // float[16(+20 pad)][512]
#define VST_OFF    (36*K*4)              // float2[512]
#define XSQ_OFF    (VST_OFF + K*8)       // float[512]
#define MPL_OFF    (XSQ_OFF + K*4)       // float[512]
#define NZ_OFF     (MPL_OFF + K*4)       // float[128]
#define DAB_OFF    (NZ_OFF + ROWS*4)     // float[128]
#define SMEM_BYTES (DAB_OFF + ROWS*4)    // 82944 B

// ---- L3-direct (bypass L1/L2) data ops: relaxed agent-scope atomics --------
__device__ __forceinline__ float ld_l3(const float* p) {
    return __uint_as_float(__hip_atomic_load((const unsigned*)p,
        __ATOMIC_RELAXED, __HIP_MEMORY_SCOPE_AGENT));
}
__device__ __forceinline__ void st_l3(float* p, float v) {
    __hip_atomic_store((unsigned*)p, __float_as_uint(v),
        __ATOMIC_RELAXED, __HIP_MEMORY_SCOPE_AGENT);
}
__device__ __forceinline__ void st_l3_2(float2* p, float2 v) {
    unsigned long long u = ((unsigned long long)__float_as_uint(v.y) << 32)
                         | (unsigned long long)__float_as_uint(v.x);
    __hip_atomic_store((unsigned long long*)p, u,
        __ATOMIC_RELAXED, __HIP_MEMORY_SCOPE_AGENT);
}
__device__ __forceinline__ float2 ld_l3_2(const float2* p) {
    unsigned long long u = __hip_atomic_load((const unsigned long long*)p,
        __ATOMIC_RELAXED, __HIP_MEMORY_SCOPE_AGENT);
    return make_float2(__uint_as_float((unsigned)(u & 0xffffffffu)),
                       __uint_as_float((unsigned)(u >> 32)));
}

// ---- DPP wave64 sum reduction (VALU pipe, zero LDS traffic) ---------------
template <int CTRL, int ROWMASK>
__device__ __forceinline__ float dppadd(float x) {
    int t = __builtin_amdgcn_update_dpp(0, __float_as_int(x), CTRL, ROWMASK,
                                        0xf, true);
    return x + __int_as_float(t);
}
__device__ __forceinline__ float wsum(float x) {
    x = dppadd<0x111, 0xf>(x);   // row_shr:1
    x = dppadd<0x112, 0xf>(x);   // row_shr:2
    x = dppadd<0x114, 0xf>(x);   // row_shr:4
    x = dppadd<0x118, 0xf>(x);   // row_shr:8
    x = dppadd<0x142, 0xa>(x);   // row_bcast:15 -> rows 1,3
    x = dppadd<0x143, 0xc>(x);   // row_bcast:31 -> rows 2,3
    return __int_as_float(__builtin_amdgcn_readlane(__float_as_int(x), 63));
}

// ---------------------------------------------------------------------------
// Quartet-split persistent kernel (round-7 structure), dwordx2 load phase.
// Block (b = blockIdx&63, q = blockIdx>>6) owns rows j0..j0+127 of batch b,
// register-resident fp16. Fragment mapping: thread (w, lane) holds rows
// {16i+w}, cols {t*128 + lane*2 + e} (t=0..3, e=0..1) -> global loads are
// 8 B/lane dwordx2 (2x in-flight bytes vs dword -> load phase BW-bound);
// all induced LDS accesses are 2-way bank aliases (free, m136).
// Per layer: P1 dot (regs+DPP->SGPR); per-row algebra on lanes 0-7; P2
// transposed matvec (regs) -> LDS reduce -> L3 partial; fence-free monotonic
// quartet barrier (thread-0 arrival, per-wave lane-0 poll); FIN whole batch
// (redundant x4, vst/xsq block-local). Cross-block data via L3-direct ops.
// ---------------------------------------------------------------------------
__global__ __launch_bounds__(NT, 4) void k_all(
    const float* __restrict__ hre,  const float* __restrict__ him,
    const float* __restrict__ noise,const float* __restrict__ mp,
    const float* __restrict__ vre,  const float* __restrict__ vim,
    const float* __restrict__ ar_re,const float* __restrict__ ar_im,
    const float* __restrict__ dl_re,const float* __restrict__ dl_im,
    const float* __restrict__ rc_re,const float* __restrict__ rc_im,
    float2* __restrict__ vtilde,    // [2][BK]
    float*  __restrict__ ulpart,    // [2][B*4][K]
    unsigned* __restrict__ bar,     // 64 quartets x 32 uints (128 B)
    float* __restrict__ out)        // [NL][BK][2]
{
    extern __shared__ char smem[];
    float*  part = (float*) (smem + PART_OFF);
    float2* vst  = (float2*)(smem + VST_OFF);
    float*  xsq  = (float*) (smem + XSQ_OFF);
    float*  mpl  = (float*) (smem + MPL_OFF);
    float*  nz   = (float*) (smem + NZ_OFF);
    float*  dab  = (float*) (smem + DAB_OFF);

    const int tid  = threadIdx.x;
    const int lane = tid & 63;
    const int w    = tid >> 6;
    const int b    = blockIdx.x & 63;          // XCD-local quartet mapping
    const int q    = blockIdx.x >> 6;
    const int j0   = q * ROWS;
    unsigned* qb   = bar + ((unsigned)b << 5);

    // ---------------- init: v state, |v|^2, maxpow, noise -------------------
    if (tid < K) {
        float a = vre[b * K + tid], c2 = vim[b * K + tid];
        vst[tid] = make_float2(a, c2);
        xsq[tid] = a * a + c2 * c2;
        mpl[tid] = mp[b * K + tid];
    } else if (tid < K + ROWS) {
        nz[tid - K] = noise[b * K + j0 + (tid - K)];
    }
    __syncthreads();

    const f2* xp = (const f2*)xsq;                 // f2 index: col/2
    float xq[8];                                   // xq[2t+e] = xsq[t*128+2*lane+e]
#pragma unroll
    for (int t = 0; t < 4; ++t) {
        f2 x = xp[t * 64 + lane];
        xq[2 * t] = x.x; xq[2 * t + 1] = x.y;
    }

    // ---------------- HBM stream -> register fragments + fused layer-0 P1 --
    half8 h[8];                                    // h[i][2t+e]
    float rs0[8];                                  // uniform row sums (l=0)
    {
        const size_t gb = ((size_t)b * K + j0) * K;     // float offset
        const f2* rp = (const f2*)(hre + gb);           // f2 offset = /2
        const f2* ip = (const f2*)(him + gb);
        f2 ra[2][4], ia[2][4];
#pragma unroll
        for (int t = 0; t < 4; ++t) {
            ra[0][t] = __builtin_nontemporal_load(rp + (size_t)w * 256 + t * 64 + lane);
            ia[0][t] = __builtin_nontemporal_load(ip + (size_t)w * 256 + t * 64 + lane);
        }
#pragma unroll
        for (int i = 0; i < 8; ++i) {
            const int cur = i & 1, nxt = cur ^ 1;
            if (i < 7) {
                const size_t rb = (size_t)(16 * (i + 1) + w) * 256;  // f2 units
#pragma unroll
                for (int t = 0; t < 4; ++t) {
                    ra[nxt][t] = __builtin_nontemporal_load(rp + rb + t * 64 + lane);
                    ia[nxt][t] = __builtin_nontemporal_load(ip + rb + t * 64 + lane);
                }
            }
            float s[8], acc = 0.f;
            half8 hh;
#pragma unroll
            for (int t = 0; t < 4; ++t) {
                const f2 r = ra[cur][t], m = ia[cur][t];
                s[2*t]   = r.x * r.x + m.x * m.x;
                s[2*t+1] = r.y * r.y + m.y * m.y;
                hh[2*t]   = (_Float16)s[2*t];
                hh[2*t+1] = (_Float16)s[2*t+1];
                acc += s[2*t] * xq[2*t] + s[2*t+1] * xq[2*t+1];
            }
            h[i] = hh;
            const int row = 16 * i + w;
            const int j   = j0 + row;              // diag at global col j
            if (lane == ((j & 127) >> 1)) dab[row] = s[((j >> 7) << 1) | (j & 1)];
            rs0[i] = wsum(acc);                    // fused layer-0 P1
        }
    }

    for (int l = 0; l < NL; ++l) {
        const int buf = l & 1;
        // ---------------- P1: row sums (regs + DPP -> SGPR) ----------------
        float scov[8];
        if (l == 0) {
#pragma unroll
            for (int r = 0; r < 8; ++r) scov[r] = rs0[r];
        } else {
#pragma unroll
            for (int t = 0; t < 4; ++t) {          // 2-way LDS alias: free
                f2 x = xp[t * 64 + lane];
                xq[2 * t] = x.x; xq[2 * t + 1] = x.y;
            }
#pragma unroll
            for (int r = 0; r < 8; ++r) {
                float acc = 0.f;
#pragma unroll
                for (int t = 0; t < 8; ++t) acc += (float)h[r][t] * xq[t];
                scov[r] = wsum(acc);
            }
        }
        // ---------------- per-row algebra: lane r owns row 16*r + w --------
        float ulv_own = 0.f;
        if (lane < 8) {
            float s = scov[0];
#pragma unroll
            for (int r = 1; r < 8; ++r) s = (lane == r) ? scov[r] : s;
            const int row = 16 * lane + w;
            const int j   = j0 + row;
            const int bj  = b * K + j;
            const float cov = s + nz[row];
            const float d2  = dab[row];
            const float A   = d2 * xsq[j];
            const float ww  = cov / (cov - A);     // w is real, > 0
            const float sc  = d2 * ww / cov;
            const float2 vv = vst[j];
            st_l3_2(&vtilde[buf * BK + bj], make_float2(sc * vv.x, sc * vv.y));
            ulv_own = A * ww / (cov * cov);        // |u|^2 |w|
        }
        float ulv[8];                              // uniform (SGPR)
#pragma unroll
        for (int r = 0; r < 8; ++r)
            ulv[r] = __int_as_float(
                __builtin_amdgcn_readlane(__float_as_int(ulv_own), r));

        // ---------------- P2: transposed matvec from register fragments ----
        f2* pp = (f2*)part;
#pragma unroll
        for (int t = 0; t < 4; ++t) {
            float a0 = 0.f, a1 = 0.f;
#pragma unroll
            for (int r = 0; r < 8; ++r) {
                a0 += (float)h[r][2*t]   * ulv[r];
                a1 += (float)h[r][2*t+1] * ulv[r];
            }
            f2 v; v.x = a0; v.y = a1;
            pp[w * 256 + t * 64 + lane] = v;       // 2-way alias: free
        }
        __syncthreads();                           // sync 1

        float s2 = 0.f;                            // own quartet partial
        if (tid < K) {
#pragma unroll
            for (int ws2 = 0; ws2 < 16; ++ws2) s2 += part[ws2 * K + tid];
            st_l3(&ulpart[(size_t)buf * (B*4*K) + ((size_t)(b*4 + q)) * K + tid],
                  s2);
        }
        __syncthreads();                           // sync 2: drain st_l3
        if (tid == 0)
            __hip_atomic_fetch_add(qb, 1u, __ATOMIC_RELAXED,
                                   __HIP_MEMORY_SCOPE_AGENT);
        if (lane == 0) {                           // per-wave poll exit
            const unsigned target = 4u * (unsigned)(l + 1);
            while (__hip_atomic_load(qb, __ATOMIC_RELAXED,
                                     __HIP_MEMORY_SCOPE_AGENT) < target)
                __builtin_amdgcn_s_sleep(2);
        }
        asm volatile("" ::: "memory");             // no hoisting past poll

        // ---------------- FIN: whole batch row (redundant x4) --------------
        if (tid < K) {
            const int k  = tid;
            const int bk = b * K + k;
            const float* up = ulpart + (size_t)buf * (B*4*K) + (size_t)(b*4) * K;
            const float2 vt = ld_l3_2(&vtilde[buf * BK + bk]);
            float ul = s2;                         // own partial: register
#pragma unroll
            for (int qq = 0; qq < 4; ++qq)
                if (qq != q) ul += ld_l3(up + qq * K + k);
            const float p   = mpl[k];
            const float avt = sqrtf(vt.x*vt.x + vt.y*vt.y);
            const float mu  = fmaxf(avt / sqrtf(p) - ul, 0.f);
            const float inv = 1.f / (ul + mu);
            float ax = 0.f, ay = 0.f;
#pragma unroll
            for (int c = 0; c < C; ++c) {
                const float gre = ar_re[c] * inv + dl_re[c];
                const float gim = ar_im[c] * inv + dl_im[c];
                float zre = vt.x * gre - vt.y * gim;
                float zim = vt.x * gim + vt.y * gre;
                zre = fmaxf(zre, 0.f);             // CReLU
                zim = fmaxf(zim, 0.f);
                ax += zre * rc_re[c] - zim * rc_im[c];
                ay += zre * rc_im[c] + zim * rc_re[c];
            }
            const float n2   = ax*ax + ay*ay;
            const float cur  = fmaxf(p, n2);
            const float corr = fminf(sqrtf(p / cur), 1.f);
            ax *= corr; ay *= corr;
            if ((k >> 7) == q)                     // owner writes out
                ((float2*)out)[(size_t)l * BK + bk] = make_float2(ax, ay);
            vst[k] = make_float2(ax, ay);
            xsq[k] = ax * ax + ay * ay;
        }
        __syncthreads();                           // sync 3
    }
}

// ---------------------------------------------------------------------------
extern "C" void kernel_launch(void* const* d_in, const int* in_sizes, int n_in,
                              void* d_out, int out_size, void* d_ws, size_t ws_size,
                              hipStream_t stream) {
    const float* hre   = (const float*)d_in[0];
    const float* him   = (const float*)d_in[1];
    const float* noise = (const float*)d_in[2];
    const float* mp    = (const float*)d_in[3];
    const float* vre   = (const float*)d_in[4];
    const float* vim   = (const float*)d_in[5];
    const float* ar_re = (const float*)d_in[6];
    const float* ar_im = (const float*)d_in[7];
    const float* dl_re = (const float*)d_in[8];
    const float* dl_im = (const float*)d_in[9];
    const float* rc_re = (const float*)d_in[10];
    const float* rc_im = (const float*)d_in[11];
    float* out = (float*)d_out;

    char*     ws     = (char*)d_ws;
    float2*   vtilde = (float2*)ws;                               // 512 KB
    float*    ulpart = (float*)(ws + 2*(size_t)BK*8);             // 1 MB
    unsigned* bar    = (unsigned*)(ws + 2*(size_t)BK*8 + 2*(size_t)B*4*K*4);

    static bool attr_done = false;
    if (!attr_done) {
        (void)hipFuncSetAttribute((const void*)k_all,
                                  hipFuncAttributeMaxDynamicSharedMemorySize,
                                  SMEM_BYTES);
        attr_done = true;
    }

    // monotonic barrier counters must be zero at kernel start on every replay
    (void)hipMemsetAsync(bar, 0, B * 32 * sizeof(unsigned), stream);

    hipLaunchKernelGGL(k_all, dim3(GRID), dim3(NT), SMEM_BYTES, stream,
                       hre, him, noise, mp, vre, vim,
                       ar_re, ar_im, dl_re, dl_im, rc_re, rc_im,
                       vtilde, ulpart, bar, out);
}